// Round 1
// baseline (255.433 us; speedup 1.0000x reference)
//
#include <hip/hip_runtime.h>

// EMA recurrence y_t = 0.1*x_t + 0.9*y_{t-1} over axis T of x[B=64][T=8192][F=64], fp32.
// Parallelized over T via chunked windup: 0.9^256 ~ 2e-12, so each chunk of L=256
// steps recovers the running state from H=256 redundant history steps (init s=0).
// lane = f  -> 64 lanes * 4B = fully coalesced 256B per wave per t-step.
// wave = one (b, chunk): 64 b * 32 chunks = 2048 waves = 8 waves/CU.

constexpr int Tn = 8192;
constexpr int Fn = 64;
constexpr int Ln = 256;   // chunk length (stores)
constexpr int Hn = 256;   // windup history length (redundant reads, no stores)
constexpr float ALPHA = 0.1f;
constexpr float OMA   = 0.9f;

__global__ __launch_bounds__(256) void ema_kernel(const float* __restrict__ x,
                                                  float* __restrict__ y) {
    const int lane = threadIdx.x & 63;       // feature index f
    const int wave = threadIdx.x >> 6;       // 0..3
    const int b    = blockIdx.x >> 3;        // 0..63   (512 blocks / 8 per b)
    const int c    = ((blockIdx.x & 7) << 2) | wave;   // chunk 0..31

    const int base = b * (Tn * Fn) + lane;
    const float* __restrict__ xp = x + base;
    float*       __restrict__ yp = y + base;

    const int t_main = c * Ln;
    float s;
    int t;
    if (c == 0) {
        // exact first element: y_0 = x_0
        s = xp[0];
        yp[0] = s;
        t = 1;
    } else {
        // windup: recover state from H history steps, init 0.
        // truncation error <= |y_{tw-1}| * 0.9^H ~ 1e-12.
        s = 0.0f;
        const int tw = t_main - Hn;
        #pragma unroll 8
        for (int i = 0; i < Hn; ++i) {
            s = fmaf(OMA, s, ALPHA * xp[(tw + i) * Fn]);
        }
        t = t_main;
    }

    const int t_end = t_main + Ln;
    #pragma unroll 8
    for (; t < t_end; ++t) {
        s = fmaf(OMA, s, ALPHA * xp[t * Fn]);
        yp[t * Fn] = s;
    }
}

extern "C" void kernel_launch(void* const* d_in, const int* in_sizes, int n_in,
                              void* d_out, int out_size, void* d_ws, size_t ws_size,
                              hipStream_t stream) {
    const float* x = (const float*)d_in[0];
    float*       y = (float*)d_out;
    // 64 b * 32 chunks = 2048 waves; 4 waves (4 consecutive chunks) per block.
    ema_kernel<<<dim3(512), dim3(256), 0, stream>>>(x, y);
}

// Round 2
// 243.749 us; speedup vs baseline: 1.0479x; 1.0479x over previous
//
#include <hip/hip_runtime.h>

// EMA y_t = 0.1*x_t + 0.9*y_{t-1} along T of x[B=64][T=8192][F=64], fp32.
// Chunked-windup parallelization over T. R2: maximize memory-level parallelism.
//   L=64  -> 128 chunks * 64 b = 8192 waves = 32 waves/CU (hw max residency)
//   H=96  -> truncation 0.9^96 ~ 4e-5, negligible vs threshold; windup reads
//            are L3-resident (R1: FETCH_SIZE stayed at 128 MB with 2x reads).
// lane = f: 64 lanes * 4 B = 256 B coalesced per wave per t-step.
// Chunks 0 and 1 computed exactly (windup anchored at y_0 = x_0).

constexpr int Tn = 8192;
constexpr int Fn = 64;
constexpr int Ln = 64;    // chunk length (stores)
constexpr int Hn = 96;    // windup history for chunks >= 2
constexpr float ALPHA = 0.1f;
constexpr float OMA   = 0.9f;

__global__ __launch_bounds__(256) void ema_kernel(const float* __restrict__ x,
                                                  float* __restrict__ y) {
    const int lane = threadIdx.x & 63;           // feature f
    const int wave = threadIdx.x >> 6;           // 0..3
    const int b    = blockIdx.x >> 5;            // 0..63
    const int c    = ((blockIdx.x & 31) << 2) | wave;  // chunk 0..127

    const int base = b * (Tn * Fn) + lane;
    const float* __restrict__ xp = x + base;
    float*       __restrict__ yp = y + base;

    const int t_main = c * Ln;
    float s;

    if (c == 0) {
        s = xp[0];
        yp[0] = s;
        #pragma unroll 16
        for (int t = 1; t < Ln; ++t) {
            s = fmaf(OMA, s, ALPHA * xp[t * Fn]);
            yp[t * Fn] = s;
        }
        return;
    } else if (c == 1) {
        // exact windup from t=0 (fixed 63-trip)
        s = xp[0];
        #pragma unroll 16
        for (int t = 1; t < Ln; ++t) {
            s = fmaf(OMA, s, ALPHA * xp[t * Fn]);
        }
    } else {
        // approximate windup: H steps from s=0; error ~ 0.9^96 * |y| ~ 1e-5
        s = 0.0f;
        const int tw = t_main - Hn;
        #pragma unroll 16
        for (int i = 0; i < Hn; ++i) {
            s = fmaf(OMA, s, ALPHA * xp[(tw + i) * Fn]);
        }
    }

    const int t_end = t_main + Ln;
    #pragma unroll 16
    for (int t = t_main; t < t_end; ++t) {
        s = fmaf(OMA, s, ALPHA * xp[t * Fn]);
        yp[t * Fn] = s;
    }
}

extern "C" void kernel_launch(void* const* d_in, const int* in_sizes, int n_in,
                              void* d_out, int out_size, void* d_ws, size_t ws_size,
                              hipStream_t stream) {
    const float* x = (const float*)d_in[0];
    float*       y = (float*)d_out;
    // 64 b * 128 chunks = 8192 waves; 4 consecutive chunks of one b per block.
    ema_kernel<<<dim3(2048), dim3(256), 0, stream>>>(x, y);
}

// Round 4
// 235.835 us; speedup vs baseline: 1.0831x; 1.0336x over previous
//
#include <hip/hip_runtime.h>

// EMA y_t = 0.1*x_t + 0.9*y_{t-1} along T of x[B=64][T=8192][F=64], fp32.
// R4 = R3 with compile fix: use native clang ext_vector float4 (HIP float4 is
// a struct -> __builtin_nontemporal_store rejects it).
// MLP attack: R2 showed VGPR=16 -> ~1KB/wave in flight -> 3.2 TB/s latency
// ceiling. Now: fx4 per lane (16 lanes/stream, 4 feature chains), explicit
// PF=16 batch prefetch (64 VGPRs of data, 16KB in flight per wave),
// L=128 / H=64 (1.5x read redundancy, 0.9^64~1.2e-3 truncation),
// nontemporal y-stores to keep x L3-resident.
// Grid: 64 b x 64 chunks, 8 streams/block (128 thr) -> 512 blocks, 4 waves/CU.

typedef float fx4 __attribute__((ext_vector_type(4)));

constexpr int Tn = 8192;
constexpr int Ln = 128;   // chunk length (stores)
constexpr int Hn = 64;    // windup history for chunks >= 1
constexpr int PF = 16;    // prefetch batch (fx4 steps)
constexpr float ALPHA = 0.1f;
constexpr float OMA   = 0.9f;

__device__ __forceinline__ void ema_step(fx4& s, const fx4 v) {
    s.x = fmaf(OMA, s.x, ALPHA * v.x);
    s.y = fmaf(OMA, s.y, ALPHA * v.y);
    s.z = fmaf(OMA, s.z, ALPHA * v.z);
    s.w = fmaf(OMA, s.w, ALPHA * v.w);
}

__global__ __launch_bounds__(128) void ema_kernel(const fx4* __restrict__ x,
                                                  fx4* __restrict__ y) {
    const int g  = threadIdx.x & 15;          // fx4 slot in feature dim
    const int sL = threadIdx.x >> 4;          // stream within block: 0..7
    const int b  = blockIdx.x >> 3;           // 0..63
    const int c  = ((blockIdx.x & 7) << 3) | sL;   // chunk 0..63

    const size_t base = (size_t)b * (Tn * 16) + g; // fx4 units; 16 fx4 per t
    const fx4* __restrict__ xp = x + base;
    fx4*       __restrict__ yp = y + base;

    const int t0 = c * Ln;
    fx4 s;
    fx4 buf[PF];
    int t, nblk;

    if (c != 0) {
        // windup: Hn steps from s=0; error <= 0.9^64 * |y| ~ 1e-3
        s = (fx4)0.0f;
        t = t0 - Hn;
        for (int blk = 0; blk < Hn / PF; ++blk) {
            #pragma unroll
            for (int i = 0; i < PF; ++i) buf[i] = xp[(size_t)(t + i) * 16];
            #pragma unroll
            for (int i = 0; i < PF; ++i) ema_step(s, buf[i]);
            t += PF;
        }
        nblk = Ln / PF;
        // t == t0 here
    } else {
        // chunk 0 exact: peel first batch, y_0 = x_0
        #pragma unroll
        for (int i = 0; i < PF; ++i) buf[i] = xp[(size_t)i * 16];
        s = buf[0];
        __builtin_nontemporal_store(s, &yp[0]);
        #pragma unroll
        for (int i = 1; i < PF; ++i) {
            ema_step(s, buf[i]);
            __builtin_nontemporal_store(s, &yp[(size_t)i * 16]);
        }
        t = PF;
        nblk = Ln / PF - 1;
    }

    // main: nblk batches of PF steps with stores
    for (int blk = 0; blk < nblk; ++blk) {
        #pragma unroll
        for (int i = 0; i < PF; ++i) buf[i] = xp[(size_t)(t + i) * 16];
        #pragma unroll
        for (int i = 0; i < PF; ++i) {
            ema_step(s, buf[i]);
            __builtin_nontemporal_store(s, &yp[(size_t)(t + i) * 16]);
        }
        t += PF;
    }
}

extern "C" void kernel_launch(void* const* d_in, const int* in_sizes, int n_in,
                              void* d_out, int out_size, void* d_ws, size_t ws_size,
                              hipStream_t stream) {
    const fx4* x = (const fx4*)d_in[0];
    fx4*       y = (fx4*)d_out;
    // 64 b * 64 chunks = 4096 streams; 8 streams (128 threads) per block.
    ema_kernel<<<dim3(512), dim3(128), 0, stream>>>(x, y);
}